// Round 4
// baseline (273.134 us; speedup 1.0000x reference)
//
#include <hip/hip_runtime.h>
#include <stdint.h>

// ---------------------------------------------------------------------------
// GroupAttentionLayer: RF=16,STRIDE=16 windows tile the image exactly =>
//   yout = leaky(Q K^T / 16) V  (full dense attention per batch), then BN +
//   spatial softmax (mu/beta cancel; only a_c = g1/sqrt(var+eps) survives).
// B=4, P=4096 px/batch (T=16384 rows), C=256. Inputs fp32, OUTPUT fp32.
// R7:  k_attn operands FRAGMENT-MAJOR in global (lane-contiguous 1KB loads).
// R8:  setprio(1) around attn MFMA phases (+7%).
// R9:  launch fusion; 1/16 folded into Q's BN coefs.
// R10: q-tile 128 experiment -> SLOWER (latency-bound at 1 blk/CU). REVERTED.
// R11 (this round): analytic BN stats BEFORE the GEMM:
//   mu_n = xbar . w_n  (column sums of Xb),  E[Y^2]_n = w_n^T G w_n / N with
//   G = Xb^T Xb (256x256 via MFMA, ~2.1 GFLOP). Both are exact reorderings of
//   the previous epilogue sums (same bf16 inputs, f32 accum). QKV GEMM then
//   applies BN+leaky+bf16 in its epilogue and writes Qf/Kf/Vf DIRECTLY
//   (LDS pack for frag-major layout): k_bn GONE, 48MB Y-write + 48MB Y-read
//   GONE (~96MB HBM saved), +2 small kernels (k_gram ~4us, k_coef2 ~6us).
//   Qf/Kf[((g*16+ks)*64+lane)*8+j] : row=g*32+(lane&31), ch=ks*16+(lane>>5)*8+j
//   Vf[((gc*256+kp)*64+lane)*8+j]  : ch=(gc&7)*32+(lane&31), key=kp*16+(lane>>5)*8+j
// ---------------------------------------------------------------------------

typedef __attribute__((ext_vector_type(8)))  short short8;   // 8 x bf16
typedef __attribute__((ext_vector_type(4)))  float f32x4;    // 16x16 acc
typedef __attribute__((ext_vector_type(16))) float f32x16;   // 32x32 acc
typedef __attribute__((ext_vector_type(4)))  unsigned short ushort4v;

#define ALPHA 0.3f
#define EPS   1e-3
#define NTOT  16384.0

__device__ __forceinline__ unsigned short f2bf(float f){
  unsigned u = __float_as_uint(f);
  u += 0x7FFFu + ((u>>16)&1u);          // RNE
  return (unsigned short)(u>>16);
}
__device__ __forceinline__ float bf2f(unsigned short u){
  return __uint_as_float((unsigned)u << 16);
}

// ------------------------------------------------- prep: cvt + wtrans + zero
// blocks [0,4096): X fp32->bf16.  blocks [4096,4864): W transpose->bf16;
// zb<257 zero G+xsum (65792 f32); zb in [257,265) zero st-tail+sums (2048 f32).
__global__ __launch_bounds__(256)
void k_prep(const float* __restrict__ X,
            const float* __restrict__ Wq,
            const float* __restrict__ Wk,
            const float* __restrict__ Wv,
            unsigned short* __restrict__ Xb,
            unsigned short* __restrict__ Wt,
            float* __restrict__ Gz, float* __restrict__ stz){
  int blk = blockIdx.x, tid = threadIdx.x;
  if (blk < 4096){
    int i = (blk*256 + tid)*4;
    float4 v = *(const float4*)(X + i);
    ushort4v o; o.x = f2bf(v.x); o.y = f2bf(v.y); o.z = f2bf(v.z); o.w = f2bf(v.w);
    *(ushort4v*)(Xb + i) = o;
  } else {
    int zb = blk - 4096;
    int o = zb*256 + tid;                        // 0 .. 196607
    int p = o >> 16, rem = o & 65535;
    int j = rem >> 8, c = rem & 255;
    const float* W = (p==0) ? Wq : ((p==1) ? Wk : Wv);
    Wt[o] = f2bf(W[c*256 + j]);
    if (zb < 257)            Gz[o] = 0.f;        // G (65536) + xsum (256)
    else if (zb < 265)       stz[(zb-257)*256 + tid] = 0.f;
  }
}

// --------------------------------------------------------------- Gram matrix
// G[c][c2] = sum_t Xb[t][c]*Xb[t][c2]  (f32 via MFMA, atomic accumulation
// over 16 K-splits of 1024 rows). Diagonal blocks also column-sum Xb -> xsum.
__global__ __launch_bounds__(256)
void k_gram(const unsigned short* __restrict__ Xb,
            float* __restrict__ G, float* __restrict__ xsum){
  __shared__ __align__(16) unsigned short At[64*72];
  __shared__ __align__(16) unsigned short Bt[64*72];
  int tid = threadIdx.x;
  int ci = blockIdx.x, cj = blockIdx.y, ks = blockIdx.z;
  bool diag = (ci == cj);
  int lane = tid & 63, wv = tid >> 6;
  int ln15 = lane & 15, quad = lane >> 4;
  int rw = (wv & 1)*32, cw = (wv >> 1)*32;
  f32x4 acc[2][2] = {};
  float xs = 0.f;
  int r0 = ks*1024;
  int trl = tid >> 3, c8 = tid & 7;
  for (int s = 0; s < 16; ++s){
    int rbase = r0 + s*64;
#pragma unroll
    for (int i2 = 0; i2 < 2; ++i2){
      int t = i2*32 + trl;
      uint4 a = *(const uint4*)(Xb + ((size_t)(rbase + t))*256 + ci*64 + c8*8);
      const unsigned short* ap = (const unsigned short*)&a;
#pragma unroll
      for (int e = 0; e < 8; ++e) At[(c8*8+e)*72 + t] = ap[e];
      if (!diag){
        uint4 b = *(const uint4*)(Xb + ((size_t)(rbase + t))*256 + cj*64 + c8*8);
        const unsigned short* bp = (const unsigned short*)&b;
#pragma unroll
        for (int e = 0; e < 8; ++e) Bt[(c8*8+e)*72 + t] = bp[e];
      }
    }
    __syncthreads();
    if (diag && tid < 64){
      float s2 = 0.f;
      for (int t = 0; t < 64; ++t) s2 += bf2f(At[tid*72 + t]);
      xs += s2;
    }
    const unsigned short* Bu = diag ? At : Bt;
#pragma unroll
    for (int k0 = 0; k0 < 2; ++k0){
      short8 af[2], bf[2];
#pragma unroll
      for (int mt = 0; mt < 2; ++mt)
        af[mt] = *(const short8*)(At + (rw+mt*16+ln15)*72 + k0*32 + quad*8);
#pragma unroll
      for (int nt = 0; nt < 2; ++nt)
        bf[nt] = *(const short8*)(Bu + (cw+nt*16+ln15)*72 + k0*32 + quad*8);
#pragma unroll
      for (int mt = 0; mt < 2; ++mt)
#pragma unroll
        for (int nt = 0; nt < 2; ++nt)
          acc[mt][nt] = __builtin_amdgcn_mfma_f32_16x16x32_bf16(af[mt], bf[nt], acc[mt][nt], 0,0,0);
    }
    __syncthreads();
  }
#pragma unroll
  for (int mt = 0; mt < 2; ++mt)
#pragma unroll
    for (int nt = 0; nt < 2; ++nt)
#pragma unroll
      for (int r = 0; r < 4; ++r){
        int gr = ci*64 + rw + mt*16 + quad*4 + r;
        int gc = cj*64 + cw + nt*16 + ln15;
        atomicAdd(&G[gr*256 + gc], acc[mt][nt][r]);
      }
  if (diag && tid < 64) atomicAdd(&xsum[ci*64 + tid], xs);
}

// --------------------------------------------------------------- BN coefs
// One block per output column n (768): mu = xsum.w/N, ms = w^T G w / N.
// scv/shv[n]: y_norm = y*scv + shv.  Q coefs carry the 1/16 score scale.
__global__ __launch_bounds__(256)
void k_coef2(const float* __restrict__ G, const float* __restrict__ xsum,
             const unsigned short* __restrict__ Wt,
             const float* __restrict__ gq, const float* __restrict__ bq,
             const float* __restrict__ gk, const float* __restrict__ bk,
             const float* __restrict__ gv, const float* __restrict__ bv,
             float* __restrict__ scv, float* __restrict__ shv){
  __shared__ float wv_s[256];
  __shared__ float red1[256], red2[256];
  int n = blockIdx.x;
  int c = threadIdx.x;
  float w = bf2f(Wt[n*256 + c]);
  wv_s[c] = w;
  __syncthreads();
  const float* gr = G + c*256;
  float dot = 0.f;
#pragma unroll 8
  for (int c2 = 0; c2 < 256; c2 += 4){
    float4 g4 = *(const float4*)(gr + c2);
    dot += g4.x*wv_s[c2] + g4.y*wv_s[c2+1] + g4.z*wv_s[c2+2] + g4.w*wv_s[c2+3];
  }
  red1[c] = w * dot;
  red2[c] = xsum[c] * w;
  __syncthreads();
  for (int off = 128; off > 0; off >>= 1){
    if (c < off){ red1[c] += red1[c+off]; red2[c] += red2[c+off]; }
    __syncthreads();
  }
  if (c == 0){
    double ms = (double)red1[0] * (1.0/NTOT);
    double mu = (double)red2[0] * (1.0/NTOT);
    double var = ms - mu*mu;
    int proj = n >> 8, ch = n & 255;
    double g = (proj==0) ? gq[ch] : (proj==1) ? gk[ch] : gv[ch];
    double b = (proj==0) ? bq[ch] : (proj==1) ? bk[ch] : bv[ch];
    double a = g / sqrt(var + EPS);
    double f = (proj==0) ? 0.0625 : 1.0;
    scv[n] = (float)(a*f);
    shv[n] = (float)((b - mu*a)*f);
  }
}

// ------------------------------------------- QKV GEMM fused BN+leaky+bf16
// Y[t][n] = sum_c Xb[t][c]*Wt[n][c]; epilogue applies y*sc+sh, lrelu, bf16,
// then LDS-packs to frag-major Qf/Kf (nb<8) or transposed frag-major Vf.
__global__ __launch_bounds__(256)
void k_qkv_gemm(const unsigned short* __restrict__ X,
                const unsigned short* __restrict__ Wt,
                const float* __restrict__ scv, const float* __restrict__ shv,
                unsigned short* __restrict__ Qf, unsigned short* __restrict__ Kf,
                unsigned short* __restrict__ Vf){
  __shared__ __align__(16) unsigned short At[64*264];
  __shared__ __align__(16) unsigned short Bt[64*264];
  __shared__ float cf_sc[64], cf_sh[64];
  int tid = threadIdx.x;
  int mb = blockIdx.x, nb = blockIdx.y;
  if (tid < 64){
    int idx = (nb < 8) ? ((nb>>2)*256 + (nb&3)*64 + tid) : (512 + (nb-8)*64 + tid);
    cf_sc[tid] = scv[idx]; cf_sh[tid] = shv[idx];
  }
#pragma unroll
  for (int it = 0; it < 8; ++it){
    int s = it*256 + tid;
    int row = s >> 5, ch = s & 31;
    uint4 a = *(const uint4*)(X  + ((size_t)(mb*64 + row))*256 + ch*8);
    uint4 b = *(const uint4*)(Wt + ((size_t)(nb*64 + row))*256 + ch*8);
    *(uint4*)(At + row*264 + ch*8) = a;
    *(uint4*)(Bt + row*264 + ch*8) = b;
  }
  __syncthreads();
  int lane = tid & 63, wv = tid >> 6;
  int ln15 = lane & 15, quad = lane >> 4;
  int rw = (wv & 1)*32, cw = (wv >> 1)*32;     // 2x2 waves, 32x32 each
  f32x4 acc[2][2] = {};
#pragma unroll
  for (int ks = 0; ks < 8; ++ks){
    short8 afr[2], bfr[2];
#pragma unroll
    for (int mt = 0; mt < 2; ++mt){
      int r = rw + mt*16 + ln15;
      afr[mt] = *(const short8*)(At + r*264 + (ks*4+quad)*8);
    }
#pragma unroll
    for (int nt = 0; nt < 2; ++nt){
      int r = cw + nt*16 + ln15;
      bfr[nt] = *(const short8*)(Bt + r*264 + (ks*4+quad)*8);
    }
#pragma unroll
    for (int mt = 0; mt < 2; ++mt)
#pragma unroll
      for (int nt = 0; nt < 2; ++nt)
        acc[mt][nt] = __builtin_amdgcn_mfma_f32_16x16x32_bf16(afr[mt], bfr[nt], acc[mt][nt], 0,0,0);
  }
  // ---- epilogue: BN + leaky + bf16 into LDS tile[64 rows][64 cols] (pad 72)
  float scr[2], shr[2];
#pragma unroll
  for (int nt = 0; nt < 2; ++nt){
    int cl = cw + nt*16 + ln15;
    scr[nt] = cf_sc[cl]; shr[nt] = cf_sh[cl];
  }
  __syncthreads();                       // done reading At/Bt
  unsigned short* tile = (unsigned short*)At;   // [64][72] = 9216B
#pragma unroll
  for (int mt = 0; mt < 2; ++mt)
#pragma unroll
    for (int nt = 0; nt < 2; ++nt)
#pragma unroll
      for (int r = 0; r < 4; ++r){
        int row = rw + mt*16 + quad*4 + r;
        int col = cw + nt*16 + ln15;
        float v = acc[mt][nt][r]*scr[nt] + shr[nt];
        tile[row*72 + col] = f2bf(fmaxf(v, ALPHA*v));
      }
  __syncthreads();
  if (nb < 8){
    // Qf/Kf: chunk = (g*16+ks)*64 + l5c*32 + l31r, 8 ch each.
    // m=(cg,row): lanes -> consecutive rows -> 2x512B contiguous runs/wave.
    unsigned short* dstB = (nb >> 2) ? Kf : Qf;
#pragma unroll
    for (int it = 0; it < 2; ++it){
      int m = it*256 + tid;
      int cg = m >> 6, row = m & 63;
      uint4 u = *(const uint4*)(tile + row*72 + cg*8);
      int ch_g = (nb&3)*64 + cg*8;
      int ksf = ch_g >> 4, l5c = (ch_g >> 3) & 1;
      int row_g = mb*64 + row;
      int g = row_g >> 5, l31r = row_g & 31;
      *(uint4*)(dstB + ((size_t)((g*16 + ksf)*64 + l5c*32 + l31r))*8) = u;
    }
  } else {
    // Vf: chunk gathers 8 consecutive pixels (t) at one channel.
    int b = mb >> 6;
#pragma unroll
    for (int it = 0; it < 2; ++it){
      int m = it*256 + tid;
      int chl = m & 63, pg = m >> 6;
      unsigned short r0 = tile[(pg*8+0)*72 + chl], r1 = tile[(pg*8+1)*72 + chl];
      unsigned short r2 = tile[(pg*8+2)*72 + chl], r3 = tile[(pg*8+3)*72 + chl];
      unsigned short r4 = tile[(pg*8+4)*72 + chl], r5 = tile[(pg*8+5)*72 + chl];
      unsigned short r6 = tile[(pg*8+6)*72 + chl], r7 = tile[(pg*8+7)*72 + chl];
      uint4 u;
      u.x = (unsigned)r0 | ((unsigned)r1<<16);
      u.y = (unsigned)r2 | ((unsigned)r3<<16);
      u.z = (unsigned)r4 | ((unsigned)r5<<16);
      u.w = (unsigned)r6 | ((unsigned)r7<<16);
      int ch_g = (nb-8)*64 + chl;
      int gc = b*8 + (ch_g >> 5), l31c = ch_g & 31;
      int kp = (mb&63)*4 + (pg >> 1), l5k = pg & 1;
      *(uint4*)(Vf + ((size_t)((gc*256 + kp)*64 + l5k*32 + l31c))*8) = u;
    }
  }
}

// --------------------------------------------------------------- attention
// R2 structure (best measured: 75us): 512 blocks x 512 threads, q-tile 64.
// blk&7 = (b,half) -> XCD-pinned. 8 iters of BK=256, 2 barriers/iter.
// setprio(1) wraps MFMA phases.
__global__ __launch_bounds__(512, 4)
void k_attn(const unsigned short* __restrict__ Qf,
            const unsigned short* __restrict__ Kf,
            const unsigned short* __restrict__ Vf,
            float* __restrict__ P0, float* __restrict__ P1){
  __shared__ __align__(16) unsigned short Ql[64*256];   // frag-major Q tile
  __shared__ __align__(16) unsigned short Sl[64*264];   // [q][key] padded
  int tid = threadIdx.x;
  int blk = blockIdx.x;
  int qt = blk >> 3, combo = blk & 7;
  int b = combo >> 1, half = combo & 1;
  int q0 = qt*64;
  int lane = tid & 63, w = tid >> 6;
  int l31 = lane & 31, l5 = lane >> 5;
  float* P = half ? P1 : P0;

  int gq0 = b*128 + qt*2;
  {
    const uint4* src = (const uint4*)(Qf + (size_t)gq0*8192);
    uint4* dst = (uint4*)Ql;
#pragma unroll
    for (int it = 0; it < 4; ++it) dst[it*512 + tid] = src[it*512 + tid];
  }
  __syncthreads();

  f32x16 acc2[2] = {};
  int gk0 = b*128 + half*64 + w;
  const unsigned short* kb = Kf + (size_t)gk0*8192 + lane*8;
  const unsigned short* vb = Vf + ((size_t)((b*8 + w)*256 + half*128))*512 + lane*8;
  const unsigned short* qa0 = Ql + lane*8;
  const unsigned short* qa1 = Ql + 16*512 + lane*8;

  for (int kt = 0; kt < 8; ++kt){
    f32x16 a1[2] = {};
    const unsigned short* kbt = kb + (size_t)kt*8*8192;
    __builtin_amdgcn_s_setprio(1);
#pragma unroll
    for (int ks = 0; ks < 16; ++ks){
      short8 kf = *(const short8*)(kbt + ks*512);
      short8 q0v = *(const short8*)(qa0 + ks*512);
      short8 q1v = *(const short8*)(qa1 + ks*512);
      a1[0] = __builtin_amdgcn_mfma_f32_32x32x16_bf16(q0v, kf, a1[0], 0, 0, 0);
      a1[1] = __builtin_amdgcn_mfma_f32_32x32x16_bf16(q1v, kf, a1[1], 0, 0, 0);
    }
    __builtin_amdgcn_s_setprio(0);
    __syncthreads();     // B0
#pragma unroll
    for (int reg = 0; reg < 16; ++reg){
      int rloc = (reg & 3) + 8*(reg >> 2) + 4*l5;
      float x0 = a1[0][reg], x1 = a1[1][reg];
      Sl[rloc*264 + w*32 + l31]        = f2bf(fmaxf(x0, 0.3f*x0));
      Sl[(32 + rloc)*264 + w*32 + l31] = f2bf(fmaxf(x1, 0.3f*x1));
    }
    __syncthreads();     // B1
    const unsigned short* vbt = vb + (size_t)kt*16*512;
    __builtin_amdgcn_s_setprio(1);
#pragma unroll
    for (int kk = 0; kk < 16; ++kk){
      short8 vf = *(const short8*)(vbt + kk*512);
      short8 s0 = *(const short8*)(Sl + (     l31)*264 + kk*16 + l5*8);
      short8 s1 = *(const short8*)(Sl + (32 + l31)*264 + kk*16 + l5*8);
      acc2[0] = __builtin_amdgcn_mfma_f32_32x32x16_bf16(s0, vf, acc2[0], 0, 0, 0);
      acc2[1] = __builtin_amdgcn_mfma_f32_32x32x16_bf16(s1, vf, acc2[1], 0, 0, 0);
    }
    __builtin_amdgcn_s_setprio(0);
  }
#pragma unroll
  for (int c = 0; c < 2; ++c)
#pragma unroll
    for (int reg = 0; reg < 16; ++reg){
      int row = q0 + c*32 + (reg & 3) + 8*(reg >> 2) + 4*l5;
      P[((size_t)b*4096 + row)*256 + w*32 + l31] = acc2[c][reg];
    }
}

// ------------------------------------------------- partial reduce + BN stats
// yout aliases P0 (in-place: each idx read before written by the same thread)
__global__ __launch_bounds__(256)
void k_red(const float* __restrict__ P0c, const float* __restrict__ P1,
           float* __restrict__ yout, double* __restrict__ st){
  int tid = threadIdx.x;
  int r0 = blockIdx.x*32;
  double sum = 0, sq = 0;
#pragma unroll 4
  for (int r = 0; r < 32; ++r){
    size_t idx = (size_t)(r0 + r)*256 + tid;
    float v = P0c[idx] + P1[idx];
    yout[idx] = v;
    sum += v; sq += (double)v*v;
  }
  atomicAdd(&st[1536 + tid], sum);
  atomicAdd(&st[1792 + tid], sq);
}

// --------------------------------------------------------------- softmax
__global__ __launch_bounds__(256)
void k_soft1(const float* __restrict__ yout, const double* __restrict__ st,
             const float* __restrict__ g1, float* __restrict__ sums){
  __shared__ float red[256];
  __shared__ float sA[64], sK[64];
  int tid = threadIdx.x;
  int chunk = blockIdx.x, ct = blockIdx.y, b = blockIdx.z;
  int cl = tid & 63, pg = tid >> 6;
  int c = ct*64 + cl;
  if (tid < 64){
    int cc = ct*64 + tid;
    double mu  = st[1536 + cc]*(1.0/NTOT);
    double var = st[1792 + cc]*(1.0/NTOT) - mu*mu;
    double a = g1[cc] / sqrt(var + EPS);
    sA[tid] = (float)a;
    sK[tid] = (float)(a*mu);
  }
  __syncthreads();
  float a = sA[cl], K = sK[cl];
  float s = 0.f;
  const float* base = yout + ((size_t)b*4096 + chunk*256)*256 + c;
#pragma unroll 4
  for (int k = 0; k < 64; ++k){
    float v = base[(size_t)(pg + k*4)*256];
    s += __expf(v*a - K);
  }
  red[tid] = s;
  __syncthreads();
  if (tid < 64){
    float tot = red[tid] + red[64+tid] + red[128+tid] + red[192+tid];
    atomicAdd(&sums[b*256 + ct*64 + tid], tot);
  }
}

__global__ __launch_bounds__(256)
void k_soft2(const float* __restrict__ yout, const double* __restrict__ st,
             const float* __restrict__ g1, const float* __restrict__ sums,
             float* __restrict__ out){
  __shared__ float sA[64], sK[64], sR[64];
  int tid = threadIdx.x;
  int chunk = blockIdx.x, ct = blockIdx.y, b = blockIdx.z;
  int cl = tid & 63, pg = tid >> 6;
  int c = ct*64 + cl;
  if (tid < 64){
    int cc = ct*64 + tid;
    double mu  = st[1536 + cc]*(1.0/NTOT);
    double var = st[1792 + cc]*(1.0/NTOT) - mu*mu;
    double a = g1[cc] / sqrt(var + EPS);
    sA[tid] = (float)a;
    sK[tid] = (float)(a*mu);
    sR[tid] = 1.f / sums[b*256 + cc];
  }
  __syncthreads();
  float a = sA[cl], K = sK[cl], rl = sR[cl];
  const float* base = yout + ((size_t)b*4096 + chunk*256)*256 + c;
  float* obase = out + ((size_t)b*4096 + chunk*256)*256 + c;
#pragma unroll 4
  for (int k = 0; k < 64; ++k){
    size_t idx = (size_t)(pg + k*4)*256;
    obase[idx] = __expf(base[idx]*a - K) * rl;
  }
}

// ---------------------------------------------------------------------------
extern "C" void kernel_launch(void* const* d_in, const int* in_sizes, int n_in,
                              void* d_out, int out_size, void* d_ws, size_t ws_size,
                              hipStream_t stream){
  (void)in_sizes; (void)n_in; (void)out_size; (void)ws_size;
  const float* X  = (const float*)d_in[0];
  const float* Wq = (const float*)d_in[1];
  const float* gq = (const float*)d_in[2];
  const float* bq = (const float*)d_in[3];
  const float* Wk = (const float*)d_in[4];
  const float* gk = (const float*)d_in[5];
  const float* bk = (const float*)d_in[6];
  const float* Wv = (const float*)d_in[7];
  const float* gv = (const float*)d_in[8];
  const float* bv = (const float*)d_in[9];
  const float* g1 = (const float*)d_in[10];
  // d_in[11] = b1: cancels inside the spatial softmax

  char* ws = (char*)d_ws;
  double*         st   = (double*)ws;                        // [1536..2048) used
  float*          stz  = (float*)(ws + 12288);               // zero target 8KB
  float*          sums = (float*)(ws + 16384);               // 4KB
  float*          scv  = (float*)(ws + 20480);               // 768 f32
  float*          shv  = (float*)(ws + 23552);               // 768 f32
  unsigned short* Wt   = (unsigned short*)(ws + 26624);      // 768x256 bf16
  unsigned short* Xb   = (unsigned short*)(ws + 419840);     // 16384x256 bf16 (8MB)
  float*          G    = (float*)(ws + 8808448);             // 256x256 f32 (256KB)
  float*          xsum = (float*)(ws + 9070592);             // 256 f32
  unsigned short* Qf   = (unsigned short*)(ws + 17301504);   // 8MB frag-major
  unsigned short* Kf   = (unsigned short*)(ws + 25690112);   // 8MB
  unsigned short* Vf   = (unsigned short*)(ws + 34078720);   // 8MB
  // P0 overlays Xb+G+xsum (dead after gemm/coef2); yo aliases P0 (in-place red)
  float*          P0   = (float*)(ws + 419840);              // 16MB, ends 17197056 < Qf
  float*          P1   = (float*)(ws + 42467328);            // 16MB
  float*          yo   = P0;

  k_prep    <<<4864, 256, 0, stream>>>(X, Wq, Wk, Wv, Xb, Wt, G, stz);
  k_gram    <<<dim3(4,4,16), 256, 0, stream>>>(Xb, G, xsum);
  k_coef2   <<<768, 256, 0, stream>>>(G, xsum, Wt, gq, bq, gk, bk, gv, bv, scv, shv);
  k_qkv_gemm<<<dim3(256,12), 256, 0, stream>>>(Xb, Wt, scv, shv, Qf, Kf, Vf);
  k_attn    <<<512, 512, 0, stream>>>(Qf, Kf, Vf, P0, P1);
  k_red     <<<512, 256, 0, stream>>>(P0, P1, yo, st);
  k_soft1   <<<dim3(16,4,4), 256, 0, stream>>>(yo, st, g1, sums);
  k_soft2   <<<dim3(16,4,4), 256, 0, stream>>>(yo, st, g1, sums, (float*)d_out);
}